// Round 5
// baseline (286.694 us; speedup 1.0000x reference)
//
#include <hip/hip_runtime.h>

#define NCH 64
#define NBLK 128          // blocks for coarse hist/scatter
#define CB 512            // coarse bins (dst >> 8)

typedef unsigned int uint;

// bf16 helpers: pack with round-to-nearest-even, unpack via bit shifts
__device__ inline uint bf16rne(float f) {
    uint u = __float_as_uint(f);
    return (u + 0x7fffu + ((u >> 16) & 1u)) >> 16;
}
__device__ inline uint pack2bf(float lo, float hi) {
    return bf16rne(lo) | (bf16rne(hi) << 16);
}
__device__ inline float unpLo(uint v) { return __uint_as_float(v << 16); }
__device__ inline float unpHi(uint v) { return __uint_as_float(v & 0xffff0000u); }

// ---------------- CSR build: two-level counting sort, LDS atomics only ----------------

__global__ void coarse_hist_kernel(const int* __restrict__ dst, int* __restrict__ cntCB,
                                   int ne, int epb) {
    __shared__ int h[CB];
    int t = threadIdx.x;
    for (int i = t; i < CB; i += blockDim.x) h[i] = 0;
    __syncthreads();
    int e0 = blockIdx.x * epb;
    int e1 = min(e0 + epb, ne);
    for (int e = e0 + t; e < e1; e += blockDim.x)
        atomicAdd(&h[dst[e] >> 8], 1);
    __syncthreads();
    for (int i = t; i < CB; i += blockDim.x) cntCB[i * NBLK + blockIdx.x] = h[i];
}

__global__ void binscan_kernel(int* __restrict__ cntCB, int* __restrict__ binTot) {
    __shared__ int s[NBLK];
    int bin = blockIdx.x;
    int t = threadIdx.x;              // NBLK threads
    int v = cntCB[bin * NBLK + t];
    s[t] = v;
    __syncthreads();
    for (int off = 1; off < NBLK; off <<= 1) {
        int add = (t >= off) ? s[t - off] : 0;
        __syncthreads();
        s[t] += add;
        __syncthreads();
    }
    cntCB[bin * NBLK + t] = s[t] - v;               // exclusive within bin
    if (t == NBLK - 1) binTot[bin] = s[t];
}

__global__ void cbscan_kernel(const int* __restrict__ binTot, int* __restrict__ cb,
                              int* __restrict__ rowptr, int n, int ne) {
    __shared__ int s[CB];
    int t = threadIdx.x;              // CB threads
    int v = binTot[t];
    s[t] = v;
    __syncthreads();
    for (int off = 1; off < CB; off <<= 1) {
        int add = (t >= off) ? s[t - off] : 0;
        __syncthreads();
        s[t] += add;
        __syncthreads();
    }
    cb[t] = s[t] - v;                               // exclusive
    if (t == CB - 1) { cb[CB] = ne; rowptr[n] = ne; }
}

__global__ void coarse_scatter_kernel(const int* __restrict__ src, const int* __restrict__ dst,
                                      const int* __restrict__ cntCB, const int* __restrict__ cb,
                                      int2* __restrict__ coarse, int ne, int epb) {
    __shared__ int cur[CB];
    int t = threadIdx.x;
    for (int i = t; i < CB; i += blockDim.x)
        cur[i] = cb[i] + cntCB[i * NBLK + blockIdx.x];
    __syncthreads();
    int e0 = blockIdx.x * epb;
    int e1 = min(e0 + epb, ne);
    for (int e = e0 + t; e < e1; e += blockDim.x) {
        int d = dst[e];
        int pos = atomicAdd(&cur[d >> 8], 1);       // LDS atomic
        coarse[pos] = make_int2(d, src[e]);
    }
}

__global__ void bucket_kernel(const int2* __restrict__ coarse, const int* __restrict__ cb,
                              int* __restrict__ rowptr, float* __restrict__ dinv,
                              int* __restrict__ csr, int n) {
    __shared__ int hist[256];
    __shared__ int excl[256];
    __shared__ int cursor[256];
    int k = blockIdx.x;
    int t = threadIdx.x;              // 256 threads
    int base = cb[k];
    int end = cb[k + 1];
    hist[t] = 0;
    __syncthreads();
    for (int i = base + t; i < end; i += 256)
        atomicAdd(&hist[coarse[i].x & 255], 1);
    __syncthreads();
    int v = hist[t];
    excl[t] = v;
    __syncthreads();
    for (int off = 1; off < 256; off <<= 1) {
        int add = (t >= off) ? excl[t - off] : 0;
        __syncthreads();
        excl[t] += add;
        __syncthreads();
    }
    int ex = excl[t] - v;                           // exclusive prefix
    int node = (k << 8) + t;
    if (node < n) {
        rowptr[node] = base + ex;
        dinv[node] = rsqrtf(1.0f + (float)v);
    }
    cursor[t] = base + ex;
    __syncthreads();
    for (int i = base + t; i < end; i += 256) {
        int2 e = coarse[i];
        int pos = atomicAdd(&cursor[e.x & 255], 1); // LDS atomic
        csr[pos] = e.y;
    }
}

// ---------------- H(bf16) = dinv[row] * (relu?)(X) @ W ----------------
template<bool RELU>
__global__ void gemm64_kernel(const float* __restrict__ X, const float* __restrict__ W,
                              const float* __restrict__ dinv, uint* __restrict__ H, int n) {
    __shared__ float Ws[NCH * NCH];
    int t = threadIdx.x;
    for (int i = t; i < NCH * NCH; i += blockDim.x) Ws[i] = W[i];
    __syncthreads();
    int row = blockIdx.x * blockDim.x + t;
    if (row >= n) return;
    const float4* xr = (const float4*)(X + (long long)row * NCH);
    float acc[NCH];
#pragma unroll
    for (int c = 0; c < NCH; ++c) acc[c] = 0.f;
#pragma unroll
    for (int k4 = 0; k4 < NCH / 4; ++k4) {
        float4 xv = xr[k4];
        if (RELU) {
            xv.x = fmaxf(xv.x, 0.f); xv.y = fmaxf(xv.y, 0.f);
            xv.z = fmaxf(xv.z, 0.f); xv.w = fmaxf(xv.w, 0.f);
        }
        float xs[4] = {xv.x, xv.y, xv.z, xv.w};
#pragma unroll
        for (int j = 0; j < 4; ++j) {
            int k = k4 * 4 + j;
#pragma unroll
            for (int c = 0; c < NCH; ++c)
                acc[c] = fmaf(xs[j], Ws[k * NCH + c], acc[c]);  // uniform LDS read -> broadcast
        }
    }
    float di = dinv[row];
    uint4* hr = (uint4*)(H + (long long)row * 32);
#pragma unroll
    for (int g = 0; g < 8; ++g) {
        uint4 pk;
        pk.x = pack2bf(di * acc[8 * g + 0], di * acc[8 * g + 1]);
        pk.y = pack2bf(di * acc[8 * g + 2], di * acc[8 * g + 3]);
        pk.z = pack2bf(di * acc[8 * g + 4], di * acc[8 * g + 5]);
        pk.w = pack2bf(di * acc[8 * g + 6], di * acc[8 * g + 7]);
        hr[g] = pk;
    }
}

// ---------------- out[d,:] = dinv[d] * (hs[d,:] + sum_{s in N(d)} hs[s,:]) + b ----------------
// one wave per node; lane = (half, channel-pair); halves process alternate edges
__global__ void agg_kernel(const uint* __restrict__ hsB, const int* __restrict__ rowptr,
                           const int* __restrict__ csr, const float* __restrict__ dinv,
                           const float* __restrict__ b, float* __restrict__ out, int n) {
    int wid = (blockIdx.x * blockDim.x + threadIdx.x) >> 6;
    if (wid >= n) return;
    int lane = threadIdx.x & 63;
    int half = lane >> 5;
    int cp = lane & 31;                               // channel pair: ch 2cp, 2cp+1
    int start = rowptr[wid];
    int end = rowptr[wid + 1];
    float ax = 0.f, ay = 0.f;
    if (!half) {                                      // self-loop counted once
        uint v = hsB[(long long)wid * 32 + cp];
        ax = unpLo(v); ay = unpHi(v);
    }
    int e = start + half;
    for (; e + 6 < end; e += 8) {                     // 4 gathers in flight per lane
        int s0 = csr[e], s1 = csr[e + 2], s2 = csr[e + 4], s3 = csr[e + 6];
        uint v0 = hsB[(long long)s0 * 32 + cp];
        uint v1 = hsB[(long long)s1 * 32 + cp];
        uint v2 = hsB[(long long)s2 * 32 + cp];
        uint v3 = hsB[(long long)s3 * 32 + cp];
        ax += (unpLo(v0) + unpLo(v1)) + (unpLo(v2) + unpLo(v3));
        ay += (unpHi(v0) + unpHi(v1)) + (unpHi(v2) + unpHi(v3));
    }
    for (; e < end; e += 2) {
        uint v = hsB[(long long)csr[e] * 32 + cp];
        ax += unpLo(v); ay += unpHi(v);
    }
    ax += __shfl_xor(ax, 32, 64);                     // combine halves
    ay += __shfl_xor(ay, 32, 64);
    if (!half) {
        float d = dinv[wid];
        float2 bv = *(const float2*)(b + 2 * cp);
        *(float2*)(out + (long long)wid * NCH + 2 * cp) =
            make_float2(d * ax + bv.x, d * ay + bv.y);
    }
}

extern "C" void kernel_launch(void* const* d_in, const int* in_sizes, int n_in,
                              void* d_out, int out_size, void* d_ws, size_t ws_size,
                              hipStream_t stream) {
    const float* x  = (const float*)d_in[0];
    const int*   ei = (const int*)d_in[1];
    const float* W1 = (const float*)d_in[2];
    const float* b1 = (const float*)d_in[3];
    const float* W2 = (const float*)d_in[4];
    const float* b2 = (const float*)d_in[5];
    const int n  = in_sizes[0] / NCH;   // 100000
    const int ne = in_sizes[1] / 2;     // 1600000
    const int* src = ei;
    const int* dst = ei + ne;
    float* out = (float*)d_out;

    // workspace layout (all 256B-aligned)
    char* ws = (char*)d_ws;
    size_t off = 0;
    auto alloc = [&](size_t bytes) { void* p = ws + off; off += (bytes + 255) & ~(size_t)255; return p; };
    int*   cntCB   = (int*)alloc((size_t)CB * NBLK * 4);       // 256 KB
    int*   binTot  = (int*)alloc((size_t)CB * 4);
    int*   cb      = (int*)alloc((size_t)(CB + 1) * 4);
    int*   rowptr  = (int*)alloc((size_t)(n + 1) * 4);
    float* dinv    = (float*)alloc((size_t)n * 4);
    int*   csr     = (int*)alloc((size_t)ne * 4);              // 6.4 MB
    int2*  coarse  = (int2*)alloc((size_t)ne * 8);             // 12.8 MB
    uint*  hsB     = (uint*)alloc((size_t)n * 32 * 4);         // 12.8 MB (bf16 features)

    const int blk = 256;
    const int gN   = (n + blk - 1) / blk;
    const int gAgg = (n * 64 + blk - 1) / blk;                 // wave per node
    const int epb  = (ne + NBLK - 1) / NBLK;
    const int nBuck = (n + 255) / 256;

    // ---- CSR build (no global atomics) ----
    coarse_hist_kernel   <<<NBLK, blk, 0, stream>>>(dst, cntCB, ne, epb);
    binscan_kernel       <<<CB, NBLK, 0, stream>>>(cntCB, binTot);
    cbscan_kernel        <<<1, CB, 0, stream>>>(binTot, cb, rowptr, n, ne);
    coarse_scatter_kernel<<<NBLK, blk, 0, stream>>>(src, dst, cntCB, cb, coarse, ne, epb);
    bucket_kernel        <<<nBuck, 256, 0, stream>>>(coarse, cb, rowptr, dinv, csr, n);

    // ---- layer 1 ----
    gemm64_kernel<false><<<gN, blk, 0, stream>>>(x, W1, dinv, hsB, n);
    agg_kernel<<<gAgg, blk, 0, stream>>>(hsB, rowptr, csr, dinv, b1, out, n);

    // ---- layer 2 (relu fused into GEMM load) ----
    gemm64_kernel<true><<<gN, blk, 0, stream>>>(out, W2, dinv, hsB, n);
    agg_kernel<<<gAgg, blk, 0, stream>>>(hsB, rowptr, csr, dinv, b2, out, n);
}

// Round 6
// 274.791 us; speedup vs baseline: 1.0433x; 1.0433x over previous
//
#include <hip/hip_runtime.h>

#define NCH 64
#define NBLK 128          // blocks for coarse hist/scatter
#define CB 512            // coarse bins (dst >> 8)

typedef unsigned int uint;

// bf16 helpers: pack with round-to-nearest-even, unpack via bit shifts
__device__ inline uint bf16rne(float f) {
    uint u = __float_as_uint(f);
    return (u + 0x7fffu + ((u >> 16) & 1u)) >> 16;
}
__device__ inline uint pack2bf(float lo, float hi) {
    return bf16rne(lo) | (bf16rne(hi) << 16);
}
__device__ inline float unpLo(uint v) { return __uint_as_float(v << 16); }
__device__ inline float unpHi(uint v) { return __uint_as_float(v & 0xffff0000u); }

// ---------------- CSR build: two-level counting sort, LDS atomics only ----------------

__global__ void coarse_hist_kernel(const int* __restrict__ dst, int* __restrict__ cntCB,
                                   int ne, int epb) {
    __shared__ int h[CB];
    int t = threadIdx.x;
    for (int i = t; i < CB; i += blockDim.x) h[i] = 0;
    __syncthreads();
    int e0 = blockIdx.x * epb;
    int e1 = min(e0 + epb, ne);
    for (int e = e0 + t; e < e1; e += blockDim.x)
        atomicAdd(&h[dst[e] >> 8], 1);
    __syncthreads();
    for (int i = t; i < CB; i += blockDim.x) cntCB[i * NBLK + blockIdx.x] = h[i];
}

__global__ void binscan_kernel(int* __restrict__ cntCB, int* __restrict__ binTot) {
    __shared__ int s[NBLK];
    int bin = blockIdx.x;
    int t = threadIdx.x;              // NBLK threads
    int v = cntCB[bin * NBLK + t];
    s[t] = v;
    __syncthreads();
    for (int off = 1; off < NBLK; off <<= 1) {
        int add = (t >= off) ? s[t - off] : 0;
        __syncthreads();
        s[t] += add;
        __syncthreads();
    }
    cntCB[bin * NBLK + t] = s[t] - v;               // exclusive within bin
    if (t == NBLK - 1) binTot[bin] = s[t];
}

__global__ void cbscan_kernel(const int* __restrict__ binTot, int* __restrict__ cb,
                              int* __restrict__ rowptr, int n, int ne) {
    __shared__ int s[CB];
    int t = threadIdx.x;              // CB threads
    int v = binTot[t];
    s[t] = v;
    __syncthreads();
    for (int off = 1; off < CB; off <<= 1) {
        int add = (t >= off) ? s[t - off] : 0;
        __syncthreads();
        s[t] += add;
        __syncthreads();
    }
    cb[t] = s[t] - v;                               // exclusive
    if (t == CB - 1) { cb[CB] = ne; rowptr[n] = ne; }
}

__global__ void coarse_scatter_kernel(const int* __restrict__ src, const int* __restrict__ dst,
                                      const int* __restrict__ cntCB, const int* __restrict__ cb,
                                      int2* __restrict__ coarse, int ne, int epb) {
    __shared__ int cur[CB];
    int t = threadIdx.x;
    for (int i = t; i < CB; i += blockDim.x)
        cur[i] = cb[i] + cntCB[i * NBLK + blockIdx.x];
    __syncthreads();
    int e0 = blockIdx.x * epb;
    int e1 = min(e0 + epb, ne);
    for (int e = e0 + t; e < e1; e += blockDim.x) {
        int d = dst[e];
        int pos = atomicAdd(&cur[d >> 8], 1);       // LDS atomic
        coarse[pos] = make_int2(d, src[e]);
    }
}

__global__ void bucket_kernel(const int2* __restrict__ coarse, const int* __restrict__ cb,
                              int* __restrict__ rowptr, float* __restrict__ dinv,
                              int* __restrict__ csr, int n) {
    __shared__ int hist[256];
    __shared__ int excl[256];
    __shared__ int cursor[256];
    int k = blockIdx.x;
    int t = threadIdx.x;              // 256 threads
    int base = cb[k];
    int end = cb[k + 1];
    hist[t] = 0;
    __syncthreads();
    for (int i = base + t; i < end; i += 256)
        atomicAdd(&hist[coarse[i].x & 255], 1);
    __syncthreads();
    int v = hist[t];
    excl[t] = v;
    __syncthreads();
    for (int off = 1; off < 256; off <<= 1) {
        int add = (t >= off) ? excl[t - off] : 0;
        __syncthreads();
        excl[t] += add;
        __syncthreads();
    }
    int ex = excl[t] - v;                           // exclusive prefix
    int node = (k << 8) + t;
    if (node < n) {
        rowptr[node] = base + ex;
        dinv[node] = rsqrtf(1.0f + (float)v);
    }
    cursor[t] = base + ex;
    __syncthreads();
    for (int i = base + t; i < end; i += 256) {
        int2 e = coarse[i];
        int pos = atomicAdd(&cursor[e.x & 255], 1); // LDS atomic
        csr[pos] = e.y;
    }
}

// ---------------- H(bf16) = dinv[row] * (relu?)(X) @ W ----------------
template<bool RELU>
__global__ void gemm64_kernel(const float* __restrict__ X, const float* __restrict__ W,
                              const float* __restrict__ dinv, uint* __restrict__ H, int n) {
    __shared__ float Ws[NCH * NCH];
    int t = threadIdx.x;
    for (int i = t; i < NCH * NCH; i += blockDim.x) Ws[i] = W[i];
    __syncthreads();
    int row = blockIdx.x * blockDim.x + t;
    if (row >= n) return;
    const float4* xr = (const float4*)(X + (long long)row * NCH);
    float acc[NCH];
#pragma unroll
    for (int c = 0; c < NCH; ++c) acc[c] = 0.f;
#pragma unroll
    for (int k4 = 0; k4 < NCH / 4; ++k4) {
        float4 xv = xr[k4];
        if (RELU) {
            xv.x = fmaxf(xv.x, 0.f); xv.y = fmaxf(xv.y, 0.f);
            xv.z = fmaxf(xv.z, 0.f); xv.w = fmaxf(xv.w, 0.f);
        }
        float xs[4] = {xv.x, xv.y, xv.z, xv.w};
#pragma unroll
        for (int j = 0; j < 4; ++j) {
            int k = k4 * 4 + j;
#pragma unroll
            for (int c = 0; c < NCH; ++c)
                acc[c] = fmaf(xs[j], Ws[k * NCH + c], acc[c]);  // uniform LDS read -> broadcast
        }
    }
    float di = dinv[row];
    uint4* hr = (uint4*)(H + (long long)row * 32);
#pragma unroll
    for (int g = 0; g < 8; ++g) {
        uint4 pk;
        pk.x = pack2bf(di * acc[8 * g + 0], di * acc[8 * g + 1]);
        pk.y = pack2bf(di * acc[8 * g + 2], di * acc[8 * g + 3]);
        pk.z = pack2bf(di * acc[8 * g + 4], di * acc[8 * g + 5]);
        pk.w = pack2bf(di * acc[8 * g + 6], di * acc[8 * g + 7]);
        hr[g] = pk;
    }
}

// ---------------- out[d,:] = dinv[d] * (hs[d,:] + sum_{s in N(d)} hs[s,:]) + b ----------------
// one wave per node; halves process alternate edges; 8 gathers in flight per lane
__global__ void agg_kernel(const uint* __restrict__ hsB, const int* __restrict__ rowptr,
                           const int* __restrict__ csr, const float* __restrict__ dinv,
                           const float* __restrict__ b, float* __restrict__ out, int n) {
    int wid = (blockIdx.x * blockDim.x + threadIdx.x) >> 6;
    if (wid >= n) return;
    int lane = threadIdx.x & 63;
    int half = lane >> 5;
    int cp = lane & 31;                               // channel pair: ch 2cp, 2cp+1
    int start = rowptr[wid];
    int end = rowptr[wid + 1];
    const uint* __restrict__ base = hsB + cp;
    float ax = 0.f, ay = 0.f;
    if (!half) {                                      // self-loop counted once
        uint v = base[(long long)wid * 32];
        ax = unpLo(v); ay = unpHi(v);
    }
    int e = start + half;
    // main loop: 16 edges per wave-iteration (8 per half), 8 gathers in flight
    for (; e + 14 < end; e += 16) {
        int s0 = csr[e],      s1 = csr[e + 2],  s2 = csr[e + 4],  s3 = csr[e + 6];
        int s4 = csr[e + 8],  s5 = csr[e + 10], s6 = csr[e + 12], s7 = csr[e + 14];
        uint v0 = base[(long long)s0 * 32];
        uint v1 = base[(long long)s1 * 32];
        uint v2 = base[(long long)s2 * 32];
        uint v3 = base[(long long)s3 * 32];
        uint v4 = base[(long long)s4 * 32];
        uint v5 = base[(long long)s5 * 32];
        uint v6 = base[(long long)s6 * 32];
        uint v7 = base[(long long)s7 * 32];
        ax += ((unpLo(v0) + unpLo(v1)) + (unpLo(v2) + unpLo(v3)))
            + ((unpLo(v4) + unpLo(v5)) + (unpLo(v6) + unpLo(v7)));
        ay += ((unpHi(v0) + unpHi(v1)) + (unpHi(v2) + unpHi(v3)))
            + ((unpHi(v4) + unpHi(v5)) + (unpHi(v6) + unpHi(v7)));
    }
    // predicated tail: up to 7 slots per half; masked slots gather row 0 (L1-hot)
    if (e < end) {
#pragma unroll
        for (int k = 0; k < 7; ++k) {
            bool c = (e + 2 * k) < end;
            int s = c ? csr[e + 2 * k] : 0;           // csr padded, index load safe
            uint v = base[(long long)s * 32];
            ax += c ? unpLo(v) : 0.f;
            ay += c ? unpHi(v) : 0.f;
        }
    }
    ax += __shfl_xor(ax, 32, 64);                     // combine halves
    ay += __shfl_xor(ay, 32, 64);
    if (!half) {
        float d = dinv[wid];
        float2 bv = *(const float2*)(b + 2 * cp);
        *(float2*)(out + (long long)wid * NCH + 2 * cp) =
            make_float2(d * ax + bv.x, d * ay + bv.y);
    }
}

extern "C" void kernel_launch(void* const* d_in, const int* in_sizes, int n_in,
                              void* d_out, int out_size, void* d_ws, size_t ws_size,
                              hipStream_t stream) {
    const float* x  = (const float*)d_in[0];
    const int*   ei = (const int*)d_in[1];
    const float* W1 = (const float*)d_in[2];
    const float* b1 = (const float*)d_in[3];
    const float* W2 = (const float*)d_in[4];
    const float* b2 = (const float*)d_in[5];
    const int n  = in_sizes[0] / NCH;   // 100000
    const int ne = in_sizes[1] / 2;     // 1600000
    const int* src = ei;
    const int* dst = ei + ne;
    float* out = (float*)d_out;

    // workspace layout (all 256B-aligned)
    char* ws = (char*)d_ws;
    size_t off = 0;
    auto alloc = [&](size_t bytes) { void* p = ws + off; off += (bytes + 255) & ~(size_t)255; return p; };
    int*   cntCB   = (int*)alloc((size_t)CB * NBLK * 4);       // 256 KB
    int*   binTot  = (int*)alloc((size_t)CB * 4);
    int*   cb      = (int*)alloc((size_t)(CB + 1) * 4);
    int*   rowptr  = (int*)alloc((size_t)(n + 1) * 4);
    float* dinv    = (float*)alloc((size_t)n * 4);
    int*   csr     = (int*)alloc((size_t)ne * 4 + 64);         // +64B pad for tail loads
    int2*  coarse  = (int2*)alloc((size_t)ne * 8);             // 12.8 MB
    uint*  hsB     = (uint*)alloc((size_t)n * 32 * 4);         // 12.8 MB (bf16 features)

    const int blk = 256;
    const int gN   = (n + blk - 1) / blk;
    const int gAgg = (n * 64 + blk - 1) / blk;                 // wave per node
    const int epb  = (ne + NBLK - 1) / NBLK;
    const int nBuck = (n + 255) / 256;

    // ---- CSR build (no global atomics) ----
    coarse_hist_kernel   <<<NBLK, blk, 0, stream>>>(dst, cntCB, ne, epb);
    binscan_kernel       <<<CB, NBLK, 0, stream>>>(cntCB, binTot);
    cbscan_kernel        <<<1, CB, 0, stream>>>(binTot, cb, rowptr, n, ne);
    coarse_scatter_kernel<<<NBLK, blk, 0, stream>>>(src, dst, cntCB, cb, coarse, ne, epb);
    bucket_kernel        <<<nBuck, 256, 0, stream>>>(coarse, cb, rowptr, dinv, csr, n);

    // ---- layer 1 ----
    gemm64_kernel<false><<<gN, blk, 0, stream>>>(x, W1, dinv, hsB, n);
    agg_kernel<<<gAgg, blk, 0, stream>>>(hsB, rowptr, csr, dinv, b1, out, n);

    // ---- layer 2 (relu fused into GEMM load) ----
    gemm64_kernel<true><<<gN, blk, 0, stream>>>(out, W2, dinv, hsB, n);
    agg_kernel<<<gAgg, blk, 0, stream>>>(hsB, rowptr, csr, dinv, b2, out, n);
}

// Round 7
// 269.658 us; speedup vs baseline: 1.0632x; 1.0190x over previous
//
#include <hip/hip_runtime.h>

#define NCH 64
#define NBLK 128          // blocks for coarse hist/scatter
#define CB 512            // coarse bins (dst >> 8)

typedef unsigned int uint;

// bf16 helpers: pack with round-to-nearest-even, unpack via bit shifts
__device__ inline uint bf16rne(float f) {
    uint u = __float_as_uint(f);
    return (u + 0x7fffu + ((u >> 16) & 1u)) >> 16;
}
__device__ inline uint pack2bf(float lo, float hi) {
    return bf16rne(lo) | (bf16rne(hi) << 16);
}
__device__ inline float unpLo(uint v) { return __uint_as_float(v << 16); }
__device__ inline float unpHi(uint v) { return __uint_as_float(v & 0xffff0000u); }

// ---------------- CSR build: two-level counting sort, LDS atomics only ----------------

__global__ void coarse_hist_kernel(const int* __restrict__ dst, int* __restrict__ cntCB,
                                   int ne, int epb) {
    __shared__ int h[CB];
    int t = threadIdx.x;
    for (int i = t; i < CB; i += blockDim.x) h[i] = 0;
    __syncthreads();
    int e0 = blockIdx.x * epb;
    int e1 = min(e0 + epb, ne);
    for (int e = e0 + t; e < e1; e += blockDim.x)
        atomicAdd(&h[dst[e] >> 8], 1);
    __syncthreads();
    for (int i = t; i < CB; i += blockDim.x) cntCB[i * NBLK + blockIdx.x] = h[i];
}

__global__ void binscan_kernel(int* __restrict__ cntCB, int* __restrict__ binTot) {
    __shared__ int s[NBLK];
    int bin = blockIdx.x;
    int t = threadIdx.x;              // NBLK threads
    int v = cntCB[bin * NBLK + t];
    s[t] = v;
    __syncthreads();
    for (int off = 1; off < NBLK; off <<= 1) {
        int add = (t >= off) ? s[t - off] : 0;
        __syncthreads();
        s[t] += add;
        __syncthreads();
    }
    cntCB[bin * NBLK + t] = s[t] - v;               // exclusive within bin
    if (t == NBLK - 1) binTot[bin] = s[t];
}

__global__ void cbscan_kernel(const int* __restrict__ binTot, int* __restrict__ cb,
                              int* __restrict__ rowptr, int n, int ne) {
    __shared__ int s[CB];
    int t = threadIdx.x;              // CB threads
    int v = binTot[t];
    s[t] = v;
    __syncthreads();
    for (int off = 1; off < CB; off <<= 1) {
        int add = (t >= off) ? s[t - off] : 0;
        __syncthreads();
        s[t] += add;
        __syncthreads();
    }
    cb[t] = s[t] - v;                               // exclusive
    if (t == CB - 1) { cb[CB] = ne; rowptr[n] = ne; }
}

__global__ void coarse_scatter_kernel(const int* __restrict__ src, const int* __restrict__ dst,
                                      const int* __restrict__ cntCB, const int* __restrict__ cb,
                                      int2* __restrict__ coarse, int ne, int epb) {
    __shared__ int cur[CB];
    int t = threadIdx.x;
    for (int i = t; i < CB; i += blockDim.x)
        cur[i] = cb[i] + cntCB[i * NBLK + blockIdx.x];
    __syncthreads();
    int e0 = blockIdx.x * epb;
    int e1 = min(e0 + epb, ne);
    for (int e = e0 + t; e < e1; e += blockDim.x) {
        int d = dst[e];
        int pos = atomicAdd(&cur[d >> 8], 1);       // LDS atomic
        coarse[pos] = make_int2(d, src[e]);
    }
}

__global__ void bucket_kernel(const int2* __restrict__ coarse, const int* __restrict__ cb,
                              int* __restrict__ rowptr, float* __restrict__ dinv,
                              int* __restrict__ csr, int n) {
    __shared__ int hist[256];
    __shared__ int excl[256];
    __shared__ int cursor[256];
    int k = blockIdx.x;
    int t = threadIdx.x;              // 256 threads
    int base = cb[k];
    int end = cb[k + 1];
    hist[t] = 0;
    __syncthreads();
    for (int i = base + t; i < end; i += 256)
        atomicAdd(&hist[coarse[i].x & 255], 1);
    __syncthreads();
    int v = hist[t];
    excl[t] = v;
    __syncthreads();
    for (int off = 1; off < 256; off <<= 1) {
        int add = (t >= off) ? excl[t - off] : 0;
        __syncthreads();
        excl[t] += add;
        __syncthreads();
    }
    int ex = excl[t] - v;                           // exclusive prefix
    int node = (k << 8) + t;
    if (node < n) {
        rowptr[node] = base + ex;
        dinv[node] = rsqrtf(1.0f + (float)v);
    }
    cursor[t] = base + ex;
    __syncthreads();
    for (int i = base + t; i < end; i += 256) {
        int2 e = coarse[i];
        int pos = atomicAdd(&cursor[e.x & 255], 1); // LDS atomic
        csr[pos] = e.y;
    }
}

// ---------------- H(bf16) = dinv[row] * (relu?)(X) @ W ----------------
// one wave per 8 rows; lane = output channel; W operand lane-spread from LDS
// (full-BW ds_read_b32), x operand extracted per (row,k) via readlane -> SGPR.
template<bool RELU>
__global__ void gemm64_kernel(const float* __restrict__ X, const float* __restrict__ W,
                              const float* __restrict__ dinv, uint* __restrict__ H, int n) {
    __shared__ float Ws[NCH * NCH];
    int t = threadIdx.x;
    // stage W: 256 threads x 4 float4
    for (int i = t; i < NCH * NCH / 4; i += 256)
        ((float4*)Ws)[i] = ((const float4*)W)[i];
    __syncthreads();

    int lane = t & 63;
    int waveId = (blockIdx.x * (blockDim.x >> 6)) + (t >> 6);
    int base = waveId * 8;                          // 8 rows per wave
    if (base >= n) return;

    // load x rows: lane l holds x[base+r][l]
    float vx[8];
#pragma unroll
    for (int r = 0; r < 8; ++r) {
        float v = X[(long long)(base + r) * NCH + lane];
        vx[r] = RELU ? fmaxf(v, 0.f) : v;
    }
    float acc[8];
#pragma unroll
    for (int r = 0; r < 8; ++r) acc[r] = 0.f;

#pragma unroll
    for (int k = 0; k < NCH; ++k) {
        float w = Ws[k * NCH + lane];               // lane-spread, conflict-free
#pragma unroll
        for (int r = 0; r < 8; ++r) {
            float xs = __uint_as_float(__builtin_amdgcn_readlane(__float_as_uint(vx[r]), k));
            acc[r] = fmaf(xs, w, acc[r]);
        }
    }

    // scale by dinv[row], pack pairs of channels to bf16, store
#pragma unroll
    for (int r = 0; r < 8; ++r) {
        float di = dinv[base + r];
        float lo = di * acc[r];
        float hi = di * __shfl_down(acc[r], 1, 64);
        if (!(lane & 1))
            H[(long long)(base + r) * 32 + (lane >> 1)] = pack2bf(lo, hi);
    }
}

// ---------------- out[d,:] = dinv[d] * (hs[d,:] + sum_{s in N(d)} hs[s,:]) + b ----------------
// one wave per node; halves process alternate edges; 8 gathers in flight per lane
__global__ void agg_kernel(const uint* __restrict__ hsB, const int* __restrict__ rowptr,
                           const int* __restrict__ csr, const float* __restrict__ dinv,
                           const float* __restrict__ b, float* __restrict__ out, int n) {
    int wid = (blockIdx.x * blockDim.x + threadIdx.x) >> 6;
    if (wid >= n) return;
    int lane = threadIdx.x & 63;
    int half = lane >> 5;
    int cp = lane & 31;                               // channel pair: ch 2cp, 2cp+1
    int start = rowptr[wid];
    int end = rowptr[wid + 1];
    const uint* __restrict__ base = hsB + cp;
    float ax = 0.f, ay = 0.f;
    if (!half) {                                      // self-loop counted once
        uint v = base[(long long)wid * 32];
        ax = unpLo(v); ay = unpHi(v);
    }
    int e = start + half;
    // main loop: 16 edges per wave-iteration (8 per half), 8 gathers in flight
    for (; e + 14 < end; e += 16) {
        int s0 = csr[e],      s1 = csr[e + 2],  s2 = csr[e + 4],  s3 = csr[e + 6];
        int s4 = csr[e + 8],  s5 = csr[e + 10], s6 = csr[e + 12], s7 = csr[e + 14];
        uint v0 = base[(long long)s0 * 32];
        uint v1 = base[(long long)s1 * 32];
        uint v2 = base[(long long)s2 * 32];
        uint v3 = base[(long long)s3 * 32];
        uint v4 = base[(long long)s4 * 32];
        uint v5 = base[(long long)s5 * 32];
        uint v6 = base[(long long)s6 * 32];
        uint v7 = base[(long long)s7 * 32];
        ax += ((unpLo(v0) + unpLo(v1)) + (unpLo(v2) + unpLo(v3)))
            + ((unpLo(v4) + unpLo(v5)) + (unpLo(v6) + unpLo(v7)));
        ay += ((unpHi(v0) + unpHi(v1)) + (unpHi(v2) + unpHi(v3)))
            + ((unpHi(v4) + unpHi(v5)) + (unpHi(v6) + unpHi(v7)));
    }
    // predicated tail: up to 7 slots per half; masked slots gather row 0 (L1-hot)
    if (e < end) {
#pragma unroll
        for (int k = 0; k < 7; ++k) {
            bool c = (e + 2 * k) < end;
            int s = c ? csr[e + 2 * k] : 0;           // csr padded, index load safe
            uint v = base[(long long)s * 32];
            ax += c ? unpLo(v) : 0.f;
            ay += c ? unpHi(v) : 0.f;
        }
    }
    ax += __shfl_xor(ax, 32, 64);                     // combine halves
    ay += __shfl_xor(ay, 32, 64);
    if (!half) {
        float d = dinv[wid];
        float2 bv = *(const float2*)(b + 2 * cp);
        *(float2*)(out + (long long)wid * NCH + 2 * cp) =
            make_float2(d * ax + bv.x, d * ay + bv.y);
    }
}

extern "C" void kernel_launch(void* const* d_in, const int* in_sizes, int n_in,
                              void* d_out, int out_size, void* d_ws, size_t ws_size,
                              hipStream_t stream) {
    const float* x  = (const float*)d_in[0];
    const int*   ei = (const int*)d_in[1];
    const float* W1 = (const float*)d_in[2];
    const float* b1 = (const float*)d_in[3];
    const float* W2 = (const float*)d_in[4];
    const float* b2 = (const float*)d_in[5];
    const int n  = in_sizes[0] / NCH;   // 100000
    const int ne = in_sizes[1] / 2;     // 1600000
    const int* src = ei;
    const int* dst = ei + ne;
    float* out = (float*)d_out;

    // workspace layout (all 256B-aligned)
    char* ws = (char*)d_ws;
    size_t off = 0;
    auto alloc = [&](size_t bytes) { void* p = ws + off; off += (bytes + 255) & ~(size_t)255; return p; };
    int*   cntCB   = (int*)alloc((size_t)CB * NBLK * 4);       // 256 KB
    int*   binTot  = (int*)alloc((size_t)CB * 4);
    int*   cb      = (int*)alloc((size_t)(CB + 1) * 4);
    int*   rowptr  = (int*)alloc((size_t)(n + 1) * 4);
    float* dinv    = (float*)alloc((size_t)n * 4);
    int*   csr     = (int*)alloc((size_t)ne * 4 + 64);         // +64B pad for tail loads
    int2*  coarse  = (int2*)alloc((size_t)ne * 8);             // 12.8 MB
    uint*  hsB     = (uint*)alloc((size_t)n * 32 * 4);         // 12.8 MB (bf16 features)

    const int blk = 256;
    const int gN   = (n + blk - 1) / blk;
    const int gAgg = (n * 64 + blk - 1) / blk;                 // wave per node
    const int epb  = (ne + NBLK - 1) / NBLK;
    const int nBuck = (n + 255) / 256;
    const int nWaves = (n + 7) / 8;                            // 8 rows per wave
    const int gGemm = (nWaves + 3) / 4;                        // 4 waves per block

    // ---- CSR build (no global atomics) ----
    coarse_hist_kernel   <<<NBLK, blk, 0, stream>>>(dst, cntCB, ne, epb);
    binscan_kernel       <<<CB, NBLK, 0, stream>>>(cntCB, binTot);
    cbscan_kernel        <<<1, CB, 0, stream>>>(binTot, cb, rowptr, n, ne);
    coarse_scatter_kernel<<<NBLK, blk, 0, stream>>>(src, dst, cntCB, cb, coarse, ne, epb);
    bucket_kernel        <<<nBuck, 256, 0, stream>>>(coarse, cb, rowptr, dinv, csr, n);

    // ---- layer 1 ----
    gemm64_kernel<false><<<gGemm, blk, 0, stream>>>(x, W1, dinv, hsB, n);
    agg_kernel<<<gAgg, blk, 0, stream>>>(hsB, rowptr, csr, dinv, b1, out, n);

    // ---- layer 2 (relu fused into GEMM load) ----
    gemm64_kernel<true><<<gGemm, blk, 0, stream>>>(out, W2, dinv, hsB, n);
    agg_kernel<<<gAgg, blk, 0, stream>>>(hsB, rowptr, csr, dinv, b2, out, n);
}

// Round 8
// 158.358 us; speedup vs baseline: 1.8104x; 1.7028x over previous
//
#include <hip/hip_runtime.h>

#define NCH 64
#define NBLK 512          // blocks for coarse hist/scatter
#define CB 512            // coarse bins (dst >> 8)

typedef unsigned int uint;
typedef short short8 __attribute__((ext_vector_type(8)));
typedef float floatx4 __attribute__((ext_vector_type(4)));

// bf16 helpers: pack with round-to-nearest-even, unpack via bit shifts
__device__ inline uint bf16rne(float f) {
    uint u = __float_as_uint(f);
    return (u + 0x7fffu + ((u >> 16) & 1u)) >> 16;
}
__device__ inline uint pack2bf(float lo, float hi) {
    return bf16rne(lo) | (bf16rne(hi) << 16);
}
__device__ inline float unpLo(uint v) { return __uint_as_float(v << 16); }
__device__ inline float unpHi(uint v) { return __uint_as_float(v & 0xffff0000u); }

// ---------------- CSR build: two-level counting sort, LDS atomics only ----------------

__global__ void coarse_hist_kernel(const int* __restrict__ dst, int* __restrict__ cntCB,
                                   int ne, int epb) {
    __shared__ int h[CB];
    int t = threadIdx.x;
    for (int i = t; i < CB; i += blockDim.x) h[i] = 0;
    __syncthreads();
    int e0 = blockIdx.x * epb;
    int e1 = min(e0 + epb, ne);
    for (int e = e0 + t; e < e1; e += blockDim.x)
        atomicAdd(&h[dst[e] >> 8], 1);
    __syncthreads();
    for (int i = t; i < CB; i += blockDim.x) cntCB[i * NBLK + blockIdx.x] = h[i];
}

__global__ void binscan_kernel(int* __restrict__ cntCB, int* __restrict__ binTot) {
    __shared__ int s[NBLK];
    int bin = blockIdx.x;
    int t = threadIdx.x;              // NBLK threads
    int v = cntCB[bin * NBLK + t];
    s[t] = v;
    __syncthreads();
    for (int off = 1; off < NBLK; off <<= 1) {
        int add = (t >= off) ? s[t - off] : 0;
        __syncthreads();
        s[t] += add;
        __syncthreads();
    }
    cntCB[bin * NBLK + t] = s[t] - v;               // exclusive within bin
    if (t == NBLK - 1) binTot[bin] = s[t];
}

__global__ void cbscan_kernel(const int* __restrict__ binTot, int* __restrict__ cb,
                              int* __restrict__ rowptr, int n, int ne) {
    __shared__ int s[CB];
    int t = threadIdx.x;              // CB threads
    int v = binTot[t];
    s[t] = v;
    __syncthreads();
    for (int off = 1; off < CB; off <<= 1) {
        int add = (t >= off) ? s[t - off] : 0;
        __syncthreads();
        s[t] += add;
        __syncthreads();
    }
    cb[t] = s[t] - v;                               // exclusive
    if (t == CB - 1) { cb[CB] = ne; rowptr[n] = ne; }
}

__global__ void coarse_scatter_kernel(const int* __restrict__ src, const int* __restrict__ dst,
                                      const int* __restrict__ cntCB, const int* __restrict__ cb,
                                      int2* __restrict__ coarse, int ne, int epb) {
    __shared__ int cur[CB];
    int t = threadIdx.x;
    for (int i = t; i < CB; i += blockDim.x)
        cur[i] = cb[i] + cntCB[i * NBLK + blockIdx.x];
    __syncthreads();
    int e0 = blockIdx.x * epb;
    int e1 = min(e0 + epb, ne);
    for (int e = e0 + t; e < e1; e += blockDim.x) {
        int d = dst[e];
        int pos = atomicAdd(&cur[d >> 8], 1);       // LDS atomic
        coarse[pos] = make_int2(d, src[e]);
    }
}

__global__ void bucket_kernel(const int2* __restrict__ coarse, const int* __restrict__ cb,
                              int* __restrict__ rowptr, float* __restrict__ dinv,
                              int* __restrict__ csr, int n) {
    __shared__ int hist[256];
    __shared__ int excl[256];
    __shared__ int cursor[256];
    int k = blockIdx.x;
    int t = threadIdx.x;              // 256 threads
    int base = cb[k];
    int end = cb[k + 1];
    hist[t] = 0;
    __syncthreads();
    for (int i = base + t; i < end; i += 256)
        atomicAdd(&hist[coarse[i].x & 255], 1);
    __syncthreads();
    int v = hist[t];
    excl[t] = v;
    __syncthreads();
    for (int off = 1; off < 256; off <<= 1) {
        int add = (t >= off) ? excl[t - off] : 0;
        __syncthreads();
        excl[t] += add;
        __syncthreads();
    }
    int ex = excl[t] - v;                           // exclusive prefix
    int node = (k << 8) + t;
    if (node < n) {
        rowptr[node] = base + ex;
        dinv[node] = rsqrtf(1.0f + (float)v);
    }
    cursor[t] = base + ex;
    __syncthreads();
    for (int i = base + t; i < end; i += 256) {
        int2 e = coarse[i];
        int pos = atomicAdd(&cursor[e.x & 255], 1); // LDS atomic
        csr[pos] = e.y;
    }
}

// ---------------- W -> bf16 MFMA B-fragments (once per call) ----------------
// frag[(mat*8 + nt*2 + kb)*64 + lane] = short8 { W[kb*32+(lane>>4)*8+j][nt*16+(lane&15)] }
__global__ void wfrag_kernel(const float* __restrict__ W1, const float* __restrict__ W2,
                             uint4* __restrict__ frag) {
    int tid = blockIdx.x * blockDim.x + threadIdx.x;   // 0..1023
    if (tid >= 1024) return;
    int mat = tid >> 9;
    int rem = tid & 511;
    int nt = rem >> 7;
    int kb = (rem >> 6) & 1;
    int lane = rem & 63;
    const float* W = mat ? W2 : W1;
    int kbase = kb * 32 + (lane >> 4) * 8;
    int col = nt * 16 + (lane & 15);
    uint r[4];
#pragma unroll
    for (int j = 0; j < 4; ++j) {
        float lo = W[(kbase + 2 * j) * NCH + col];
        float hi = W[(kbase + 2 * j + 1) * NCH + col];
        r[j] = pack2bf(lo, hi);                       // slot 2j low, 2j+1 high (ascending k)
    }
    frag[tid] = make_uint4(r[0], r[1], r[2], r[3]);
}

// ---------------- H(bf16) = dinv[row] * (relu?)(X) @ W via MFMA ----------------
// one wave per 16 rows; A packed with the SAME ascending-k slot order as wfrag,
// so the k-sum is correct for any consistent HW slot->k mapping.
// Output word w of row = channels (w, w+32):  hsB[row][w] = pack(h[w], h[w+32]).
template<bool RELU>
__global__ void gemm_mfma_kernel(const float* __restrict__ X, const uint4* __restrict__ wfrag,
                                 const float* __restrict__ dinv, uint* __restrict__ H, int n) {
    int lane = threadIdx.x & 63;
    int wave = blockIdx.x * (blockDim.x >> 6) + (threadIdx.x >> 6);
    int rb = wave * 16;
    if (rb >= n) return;

    // B fragments: broadcast 8 KB, L1/L2-hot
    short8 bfrag[4][2];
#pragma unroll
    for (int nt = 0; nt < 4; ++nt)
#pragma unroll
        for (int kb = 0; kb < 2; ++kb) {
            uint4 u = wfrag[(nt * 2 + kb) * 64 + lane];
            bfrag[nt][kb] = *(short8*)&u;
        }

    // A fragments: row = rb + (lane&15), k = kb*32 + (lane>>4)*8 + j
    const float* xr = X + (long long)(rb + (lane & 15)) * NCH + (lane >> 4) * 8;
    short8 afrag[2];
#pragma unroll
    for (int kb = 0; kb < 2; ++kb) {
        float4 v0 = *(const float4*)(xr + kb * 32);
        float4 v1 = *(const float4*)(xr + kb * 32 + 4);
        if (RELU) {
            v0.x = fmaxf(v0.x, 0.f); v0.y = fmaxf(v0.y, 0.f);
            v0.z = fmaxf(v0.z, 0.f); v0.w = fmaxf(v0.w, 0.f);
            v1.x = fmaxf(v1.x, 0.f); v1.y = fmaxf(v1.y, 0.f);
            v1.z = fmaxf(v1.z, 0.f); v1.w = fmaxf(v1.w, 0.f);
        }
        short8 a;
        a[0] = (short)bf16rne(v0.x); a[1] = (short)bf16rne(v0.y);
        a[2] = (short)bf16rne(v0.z); a[3] = (short)bf16rne(v0.w);
        a[4] = (short)bf16rne(v1.x); a[5] = (short)bf16rne(v1.y);
        a[6] = (short)bf16rne(v1.z); a[7] = (short)bf16rne(v1.w);
        afrag[kb] = a;
    }

    floatx4 acc[4];
#pragma unroll
    for (int nt = 0; nt < 4; ++nt) acc[nt] = (floatx4){0.f, 0.f, 0.f, 0.f};
#pragma unroll
    for (int nt = 0; nt < 4; ++nt)
#pragma unroll
        for (int kb = 0; kb < 2; ++kb)
            acc[nt] = __builtin_amdgcn_mfma_f32_16x16x32_bf16(afrag[kb], bfrag[nt][kb], acc[nt], 0, 0, 0);

    // D: col = nt*16 + (lane&15), row = rb + (lane>>4)*4 + reg  (HW-verified layout)
    int r0 = rb + (lane >> 4) * 4;
#pragma unroll
    for (int reg = 0; reg < 4; ++reg) {
        float di = dinv[r0 + reg];
        long long roww = (long long)(r0 + reg) * 32;
#pragma unroll
        for (int nt = 0; nt < 2; ++nt) {
            int w = nt * 16 + (lane & 15);
            H[roww + w] = pack2bf(di * acc[nt][reg], di * acc[nt + 2][reg]);
        }
    }
}

// ---------------- out[d,:] = dinv[d] * (hs[d,:] + sum_{s in N(d)} hs[s,:]) + b ----------------
// one wave per node; 4 quarters x 16 lanes; uint2 gathers (4 rows / instruction);
// word w of a row = channels (w, w+32)
__global__ void agg_kernel(const uint* __restrict__ hsB, const int* __restrict__ rowptr,
                           const int* __restrict__ csr, const float* __restrict__ dinv,
                           const float* __restrict__ b, float* __restrict__ out, int n) {
    int wid = (blockIdx.x * blockDim.x + threadIdx.x) >> 6;
    if (wid >= n) return;
    wid = __builtin_amdgcn_readfirstlane(wid);        // force SGPR: rowptr/dinv scalar loads
    int lane = threadIdx.x & 63;
    int q = lane >> 4;                                // quarter: which edges
    int u = lane & 15;                                // uint2 index: words 2u, 2u+1
    int start = rowptr[wid];
    int end = rowptr[wid + 1];
    const uint2* __restrict__ base = (const uint2*)hsB + u;
    float ax0 = 0.f, ax1 = 0.f, ay0 = 0.f, ay1 = 0.f; // ch 2u, 2u+1, 2u+32, 2u+33
    if (q == 0) {                                     // self-loop counted once
        uint2 v = base[(long long)wid * 16];
        ax0 = unpLo(v.x); ay0 = unpHi(v.x); ax1 = unpLo(v.y); ay1 = unpHi(v.y);
    }
    int eb = start;
    for (; eb + 16 <= end; eb += 16) {                // uniform loop; 4 gathers in flight/lane
        int s0 = csr[eb + q], s1 = csr[eb + q + 4], s2 = csr[eb + q + 8], s3 = csr[eb + q + 12];
        uint2 v0 = base[(long long)s0 * 16];
        uint2 v1 = base[(long long)s1 * 16];
        uint2 v2 = base[(long long)s2 * 16];
        uint2 v3 = base[(long long)s3 * 16];
        ax0 += (unpLo(v0.x) + unpLo(v1.x)) + (unpLo(v2.x) + unpLo(v3.x));
        ay0 += (unpHi(v0.x) + unpHi(v1.x)) + (unpHi(v2.x) + unpHi(v3.x));
        ax1 += (unpLo(v0.y) + unpLo(v1.y)) + (unpLo(v2.y) + unpLo(v3.y));
        ay1 += (unpHi(v0.y) + unpHi(v1.y)) + (unpHi(v2.y) + unpHi(v3.y));
    }
    if (eb < end) {                                   // predicated tail (csr padded)
#pragma unroll
        for (int k = 0; k < 4; ++k) {
            int idx = eb + q + 4 * k;
            bool c = idx < end;
            int s = csr[idx];
            s = c ? s : 0;
            uint2 v = base[(long long)s * 16];
            ax0 += c ? unpLo(v.x) : 0.f;
            ay0 += c ? unpHi(v.x) : 0.f;
            ax1 += c ? unpLo(v.y) : 0.f;
            ay1 += c ? unpHi(v.y) : 0.f;
        }
    }
    // combine quarters
    ax0 += __shfl_xor(ax0, 16, 64); ay0 += __shfl_xor(ay0, 16, 64);
    ax1 += __shfl_xor(ax1, 16, 64); ay1 += __shfl_xor(ay1, 16, 64);
    ax0 += __shfl_xor(ax0, 32, 64); ay0 += __shfl_xor(ay0, 32, 64);
    ax1 += __shfl_xor(ax1, 32, 64); ay1 += __shfl_xor(ay1, 32, 64);
    if (q == 0) {
        float d = dinv[wid];
        float2 blo = *(const float2*)(b + 2 * u);
        float2 bhi = *(const float2*)(b + 2 * u + 32);
        *(float2*)(out + (long long)wid * NCH + 2 * u) =
            make_float2(d * ax0 + blo.x, d * ax1 + blo.y);
        *(float2*)(out + (long long)wid * NCH + 2 * u + 32) =
            make_float2(d * ay0 + bhi.x, d * ay1 + bhi.y);
    }
}

extern "C" void kernel_launch(void* const* d_in, const int* in_sizes, int n_in,
                              void* d_out, int out_size, void* d_ws, size_t ws_size,
                              hipStream_t stream) {
    const float* x  = (const float*)d_in[0];
    const int*   ei = (const int*)d_in[1];
    const float* W1 = (const float*)d_in[2];
    const float* b1 = (const float*)d_in[3];
    const float* W2 = (const float*)d_in[4];
    const float* b2 = (const float*)d_in[5];
    const int n  = in_sizes[0] / NCH;   // 100000
    const int ne = in_sizes[1] / 2;     // 1600000
    const int* src = ei;
    const int* dst = ei + ne;
    float* out = (float*)d_out;

    // workspace layout (all 256B-aligned)
    char* ws = (char*)d_ws;
    size_t off = 0;
    auto alloc = [&](size_t bytes) { void* p = ws + off; off += (bytes + 255) & ~(size_t)255; return p; };
    int*   cntCB   = (int*)alloc((size_t)CB * NBLK * 4);       // 1 MB
    int*   binTot  = (int*)alloc((size_t)CB * 4);
    int*   cb      = (int*)alloc((size_t)(CB + 1) * 4);
    int*   rowptr  = (int*)alloc((size_t)(n + 1) * 4);
    float* dinv    = (float*)alloc((size_t)n * 4);
    int*   csr     = (int*)alloc((size_t)ne * 4 + 64);         // +64B pad for tail loads
    int2*  coarse  = (int2*)alloc((size_t)ne * 8);             // 12.8 MB
    uint*  hsB     = (uint*)alloc((size_t)n * 32 * 4);         // 12.8 MB (bf16 features)
    uint4* wfrag   = (uint4*)alloc(1024 * 16);                 // 16 KB (both layers' B-frags)

    const int blk = 256;
    const int gAgg = (n * 64 + blk - 1) / blk;                 // wave per node
    const int epb  = (ne + NBLK - 1) / NBLK;
    const int nBuck = (n + 255) / 256;
    const int nWaveG = (n + 15) / 16;                          // 16 rows per wave
    const int gGemm = (nWaveG + 3) / 4;                        // 4 waves per block

    // ---- CSR build (no global atomics) + W fragment pack ----
    wfrag_kernel         <<<4, 256, 0, stream>>>(W1, W2, wfrag);
    coarse_hist_kernel   <<<NBLK, blk, 0, stream>>>(dst, cntCB, ne, epb);
    binscan_kernel       <<<CB, NBLK, 0, stream>>>(cntCB, binTot);
    cbscan_kernel        <<<1, CB, 0, stream>>>(binTot, cb, rowptr, n, ne);
    coarse_scatter_kernel<<<NBLK, blk, 0, stream>>>(src, dst, cntCB, cb, coarse, ne, epb);
    bucket_kernel        <<<nBuck, 256, 0, stream>>>(coarse, cb, rowptr, dinv, csr, n);

    // ---- layer 1 ----
    gemm_mfma_kernel<false><<<gGemm, blk, 0, stream>>>(x, wfrag, dinv, hsB, n);
    agg_kernel<<<gAgg, blk, 0, stream>>>(hsB, rowptr, csr, dinv, b1, out, n);

    // ---- layer 2 (relu fused into GEMM A-load) ----
    gemm_mfma_kernel<true><<<gGemm, blk, 0, stream>>>(out, wfrag + 512, dinv, hsB, n);
    agg_kernel<<<gAgg, blk, 0, stream>>>(hsB, rowptr, csr, dinv, b2, out, n);
}

// Round 9
// 158.186 us; speedup vs baseline: 1.8124x; 1.0011x over previous
//
#include <hip/hip_runtime.h>

#define NCH 64
#define NBLK 512          // blocks for coarse hist/scatter
#define CB 512            // coarse bins (dst >> 8)

typedef unsigned int uint;
typedef short short8 __attribute__((ext_vector_type(8)));
typedef float floatx4 __attribute__((ext_vector_type(4)));

// bf16 helpers: pack with round-to-nearest-even, unpack via bit shifts
__device__ inline uint bf16rne(float f) {
    uint u = __float_as_uint(f);
    return (u + 0x7fffu + ((u >> 16) & 1u)) >> 16;
}
__device__ inline uint pack2bf(float lo, float hi) {
    return bf16rne(lo) | (bf16rne(hi) << 16);
}
__device__ inline float unpLo(uint v) { return __uint_as_float(v << 16); }
__device__ inline float unpHi(uint v) { return __uint_as_float(v & 0xffff0000u); }

// ---------------- CSR build: two-level counting sort, LDS atomics only ----------------

__global__ void coarse_hist_kernel(const int* __restrict__ dst, int* __restrict__ cntCB,
                                   int ne, int epb) {
    __shared__ int h[CB];
    int t = threadIdx.x;
    for (int i = t; i < CB; i += blockDim.x) h[i] = 0;
    __syncthreads();
    int e0 = blockIdx.x * epb;
    int e1 = min(e0 + epb, ne);
    for (int e = e0 + t; e < e1; e += blockDim.x)
        atomicAdd(&h[dst[e] >> 8], 1);
    __syncthreads();
    for (int i = t; i < CB; i += blockDim.x) cntCB[i * NBLK + blockIdx.x] = h[i];
}

__global__ void binscan_kernel(int* __restrict__ cntCB, int* __restrict__ binTot) {
    __shared__ int s[NBLK];
    int bin = blockIdx.x;
    int t = threadIdx.x;              // NBLK threads
    int v = cntCB[bin * NBLK + t];
    s[t] = v;
    __syncthreads();
    for (int off = 1; off < NBLK; off <<= 1) {
        int add = (t >= off) ? s[t - off] : 0;
        __syncthreads();
        s[t] += add;
        __syncthreads();
    }
    cntCB[bin * NBLK + t] = s[t] - v;               // exclusive within bin
    if (t == NBLK - 1) binTot[bin] = s[t];
}

__global__ void cbscan_kernel(const int* __restrict__ binTot, int* __restrict__ cb,
                              int* __restrict__ rowptr, int n, int ne) {
    __shared__ int s[CB];
    int t = threadIdx.x;              // CB threads
    int v = binTot[t];
    s[t] = v;
    __syncthreads();
    for (int off = 1; off < CB; off <<= 1) {
        int add = (t >= off) ? s[t - off] : 0;
        __syncthreads();
        s[t] += add;
        __syncthreads();
    }
    cb[t] = s[t] - v;                               // exclusive
    if (t == CB - 1) { cb[CB] = ne; rowptr[n] = ne; }
}

__global__ void coarse_scatter_kernel(const int* __restrict__ src, const int* __restrict__ dst,
                                      const int* __restrict__ cntCB, const int* __restrict__ cb,
                                      int2* __restrict__ coarse, int ne, int epb) {
    __shared__ int cur[CB];
    int t = threadIdx.x;
    for (int i = t; i < CB; i += blockDim.x)
        cur[i] = cb[i] + cntCB[i * NBLK + blockIdx.x];
    __syncthreads();
    int e0 = blockIdx.x * epb;
    int e1 = min(e0 + epb, ne);
    for (int e = e0 + t; e < e1; e += blockDim.x) {
        int d = dst[e];
        int pos = atomicAdd(&cur[d >> 8], 1);       // LDS atomic
        coarse[pos] = make_int2(d, src[e]);
    }
}

__global__ void bucket_kernel(const int2* __restrict__ coarse, const int* __restrict__ cb,
                              int* __restrict__ rowptr, float* __restrict__ dinv,
                              int* __restrict__ csr, int n) {
    __shared__ int hist[256];
    __shared__ int excl[256];
    __shared__ int cursor[256];
    int k = blockIdx.x;
    int t = threadIdx.x;              // 256 threads
    int base = cb[k];
    int end = cb[k + 1];
    hist[t] = 0;
    __syncthreads();
    for (int i = base + t; i < end; i += 256)
        atomicAdd(&hist[coarse[i].x & 255], 1);
    __syncthreads();
    int v = hist[t];
    excl[t] = v;
    __syncthreads();
    for (int off = 1; off < 256; off <<= 1) {
        int add = (t >= off) ? excl[t - off] : 0;
        __syncthreads();
        excl[t] += add;
        __syncthreads();
    }
    int ex = excl[t] - v;                           // exclusive prefix
    int node = (k << 8) + t;
    if (node < n) {
        rowptr[node] = base + ex;
        dinv[node] = rsqrtf(1.0f + (float)v);
    }
    cursor[t] = base + ex;
    __syncthreads();
    for (int i = base + t; i < end; i += 256) {
        int2 e = coarse[i];
        int pos = atomicAdd(&cursor[e.x & 255], 1); // LDS atomic
        csr[pos] = e.y;
    }
}

// ---------------- W -> bf16 MFMA B-fragments (once per call) ----------------
__global__ void wfrag_kernel(const float* __restrict__ W1, const float* __restrict__ W2,
                             uint4* __restrict__ frag) {
    int tid = blockIdx.x * blockDim.x + threadIdx.x;   // 0..1023
    if (tid >= 1024) return;
    int mat = tid >> 9;
    int rem = tid & 511;
    int nt = rem >> 7;
    int kb = (rem >> 6) & 1;
    int lane = rem & 63;
    const float* W = mat ? W2 : W1;
    int kbase = kb * 32 + (lane >> 4) * 8;
    int col = nt * 16 + (lane & 15);
    uint r[4];
#pragma unroll
    for (int j = 0; j < 4; ++j) {
        float lo = W[(kbase + 2 * j) * NCH + col];
        float hi = W[(kbase + 2 * j + 1) * NCH + col];
        r[j] = pack2bf(lo, hi);                       // slot 2j low, 2j+1 high (ascending k)
    }
    frag[tid] = make_uint4(r[0], r[1], r[2], r[3]);
}

// ---------------- H(bf16) = dinv[row] * X @ W via MFMA ----------------
// BF16A=false: X is f32 rows. BF16A=true: X is bf16 rows in (w,w+32)-packed
// uint words (relu already applied by the producer).
// Output word w of row = channels (w, w+32):  H[row][w] = pack(h[w], h[w+32]).
template<bool BF16A>
__global__ void gemm_mfma_kernel(const void* __restrict__ Xv, const uint4* __restrict__ wfrag,
                                 const float* __restrict__ dinv, uint* __restrict__ H, int n) {
    int lane = threadIdx.x & 63;
    int wave = blockIdx.x * (blockDim.x >> 6) + (threadIdx.x >> 6);
    int rb = wave * 16;
    if (rb >= n) return;

    // B fragments: broadcast 8 KB, L1/L2-hot
    short8 bfrag[4][2];
#pragma unroll
    for (int nt = 0; nt < 4; ++nt)
#pragma unroll
        for (int kb = 0; kb < 2; ++kb) {
            uint4 u = wfrag[(nt * 2 + kb) * 64 + lane];
            bfrag[nt][kb] = *(short8*)&u;
        }

    // A fragments: row = rb + (lane&15), k = kb*32 + (lane>>4)*8 + j
    short8 afrag[2];
    if (BF16A) {
        const uint* hr = (const uint*)Xv + (long long)(rb + (lane & 15)) * 32 + (lane >> 4) * 8;
        uint4 a0 = *(const uint4*)(hr);         // words kbase..kbase+3
        uint4 a1 = *(const uint4*)(hr + 4);     // words kbase+4..kbase+7
        uint w[8] = {a0.x, a0.y, a0.z, a0.w, a1.x, a1.y, a1.z, a1.w};
        short8 f0, f1;
#pragma unroll
        for (int j = 0; j < 8; ++j) {
            f0[j] = (short)(w[j] & 0xffffu);    // ch kbase+j      (kb=0)
            f1[j] = (short)(w[j] >> 16);        // ch 32+kbase+j   (kb=1)
        }
        afrag[0] = f0;
        afrag[1] = f1;
    } else {
        const float* xr = (const float*)Xv + (long long)(rb + (lane & 15)) * NCH + (lane >> 4) * 8;
#pragma unroll
        for (int kb = 0; kb < 2; ++kb) {
            float4 v0 = *(const float4*)(xr + kb * 32);
            float4 v1 = *(const float4*)(xr + kb * 32 + 4);
            short8 a;
            a[0] = (short)bf16rne(v0.x); a[1] = (short)bf16rne(v0.y);
            a[2] = (short)bf16rne(v0.z); a[3] = (short)bf16rne(v0.w);
            a[4] = (short)bf16rne(v1.x); a[5] = (short)bf16rne(v1.y);
            a[6] = (short)bf16rne(v1.z); a[7] = (short)bf16rne(v1.w);
            afrag[kb] = a;
        }
    }

    floatx4 acc[4];
#pragma unroll
    for (int nt = 0; nt < 4; ++nt) acc[nt] = (floatx4){0.f, 0.f, 0.f, 0.f};
#pragma unroll
    for (int nt = 0; nt < 4; ++nt)
#pragma unroll
        for (int kb = 0; kb < 2; ++kb)
            acc[nt] = __builtin_amdgcn_mfma_f32_16x16x32_bf16(afrag[kb], bfrag[nt][kb], acc[nt], 0, 0, 0);

    // D: col = nt*16 + (lane&15), row = rb + (lane>>4)*4 + reg  (HW-verified layout)
    int r0 = rb + (lane >> 4) * 4;
#pragma unroll
    for (int reg = 0; reg < 4; ++reg) {
        float di = dinv[r0 + reg];
        long long roww = (long long)(r0 + reg) * 32;
#pragma unroll
        for (int nt = 0; nt < 2; ++nt) {
            int w = nt * 16 + (lane & 15);
            H[roww + w] = pack2bf(di * acc[nt][reg], di * acc[nt + 2][reg]);
        }
    }
}

// ---------------- agg: out[d,:] = act( dinv[d] * (hs[d,:] + sum_{s in N(d)} hs[s,:]) + b ) ----
// one wave per node; 4 quarters x 16 lanes; uint2 gathers; 32-edge rounds with
// all 8 gathers in flight; contiguous dwordx4 csr index loads; predicated dual tail.
// BF16OUT: write relu'd bf16 (w,w+32)-packed words; else f32.
template<bool BF16OUT>
__global__ void agg_kernel(const uint* __restrict__ hsB, const int* __restrict__ rowptr,
                           const int* __restrict__ csr, const float* __restrict__ dinv,
                           const float* __restrict__ b, void* __restrict__ outv, int n) {
    int wid = (blockIdx.x * blockDim.x + threadIdx.x) >> 6;
    if (wid >= n) return;
    wid = __builtin_amdgcn_readfirstlane(wid);        // force SGPR: rowptr/dinv scalar loads
    int lane = threadIdx.x & 63;
    int q = lane >> 4;                                // quarter: which edges
    int u = lane & 15;                                // uint2 index: words 2u, 2u+1
    int start = rowptr[wid];
    int end = rowptr[wid + 1];
    const uint2* __restrict__ base = (const uint2*)hsB + u;
    float ax0 = 0.f, ax1 = 0.f, ay0 = 0.f, ay1 = 0.f; // ch 2u, 2u+1, 2u+32, 2u+33
    if (q == 0) {                                     // self-loop counted once
        uint2 v = base[(long long)wid * 16];
        ax0 = unpLo(v.x); ay0 = unpHi(v.x); ax1 = unpLo(v.y); ay1 = unpHi(v.y);
    }
    int eb = start;
    // main: 32 edges/round, quarter q owns edges eb+16r+4q+k (r=0,1; k=0..3)
    for (; eb + 32 <= end; eb += 32) {
        int4 i0, i1;
        __builtin_memcpy(&i0, csr + eb + 4 * q, 16);        // dwordx4, 4B-align safe
        __builtin_memcpy(&i1, csr + eb + 16 + 4 * q, 16);
        uint2 v0 = base[(long long)i0.x * 16];
        uint2 v1 = base[(long long)i0.y * 16];
        uint2 v2 = base[(long long)i0.z * 16];
        uint2 v3 = base[(long long)i0.w * 16];
        uint2 v4 = base[(long long)i1.x * 16];
        uint2 v5 = base[(long long)i1.y * 16];
        uint2 v6 = base[(long long)i1.z * 16];
        uint2 v7 = base[(long long)i1.w * 16];
        ax0 += ((unpLo(v0.x) + unpLo(v1.x)) + (unpLo(v2.x) + unpLo(v3.x)))
             + ((unpLo(v4.x) + unpLo(v5.x)) + (unpLo(v6.x) + unpLo(v7.x)));
        ay0 += ((unpHi(v0.x) + unpHi(v1.x)) + (unpHi(v2.x) + unpHi(v3.x)))
             + ((unpHi(v4.x) + unpHi(v5.x)) + (unpHi(v6.x) + unpHi(v7.x)));
        ax1 += ((unpLo(v0.y) + unpLo(v1.y)) + (unpLo(v2.y) + unpLo(v3.y)))
             + ((unpLo(v4.y) + unpLo(v5.y)) + (unpLo(v6.y) + unpLo(v7.y)));
        ay1 += ((unpHi(v0.y) + unpHi(v1.y)) + (unpHi(v2.y) + unpHi(v3.y)))
             + ((unpHi(v4.y) + unpHi(v5.y)) + (unpHi(v6.y) + unpHi(v7.y)));
    }
    // predicated dual tail: up to 31 edges; csr padded 128B; masked -> row 0
    if (eb < end) {
        int4 i0, i1;
        __builtin_memcpy(&i0, csr + eb + 4 * q, 16);
        __builtin_memcpy(&i1, csr + eb + 16 + 4 * q, 16);
        int s[8] = {i0.x, i0.y, i0.z, i0.w, i1.x, i1.y, i1.z, i1.w};
#pragma unroll
        for (int k = 0; k < 8; ++k) {
            int idx = eb + 16 * (k >> 2) + 4 * q + (k & 3);
            bool c = idx < end;
            int sk = c ? s[k] : 0;
            uint2 v = base[(long long)sk * 16];
            ax0 += c ? unpLo(v.x) : 0.f;
            ay0 += c ? unpHi(v.x) : 0.f;
            ax1 += c ? unpLo(v.y) : 0.f;
            ay1 += c ? unpHi(v.y) : 0.f;
        }
    }
    // combine quarters
    ax0 += __shfl_xor(ax0, 16, 64); ay0 += __shfl_xor(ay0, 16, 64);
    ax1 += __shfl_xor(ax1, 16, 64); ay1 += __shfl_xor(ay1, 16, 64);
    ax0 += __shfl_xor(ax0, 32, 64); ay0 += __shfl_xor(ay0, 32, 64);
    ax1 += __shfl_xor(ax1, 32, 64); ay1 += __shfl_xor(ay1, 32, 64);
    if (q == 0) {
        float d = dinv[wid];
        float2 blo = *(const float2*)(b + 2 * u);
        float2 bhi = *(const float2*)(b + 2 * u + 32);
        float r00 = d * ax0 + blo.x;   // ch 2u
        float r01 = d * ax1 + blo.y;   // ch 2u+1
        float r10 = d * ay0 + bhi.x;   // ch 2u+32
        float r11 = d * ay1 + bhi.y;   // ch 2u+33
        if (BF16OUT) {
            uint w0 = pack2bf(fmaxf(r00, 0.f), fmaxf(r10, 0.f));  // word 2u
            uint w1 = pack2bf(fmaxf(r01, 0.f), fmaxf(r11, 0.f));  // word 2u+1
            *((uint2*)outv + (long long)wid * 16 + u) = make_uint2(w0, w1);
        } else {
            float* out = (float*)outv;
            *(float2*)(out + (long long)wid * NCH + 2 * u) = make_float2(r00, r01);
            *(float2*)(out + (long long)wid * NCH + 2 * u + 32) = make_float2(r10, r11);
        }
    }
}

extern "C" void kernel_launch(void* const* d_in, const int* in_sizes, int n_in,
                              void* d_out, int out_size, void* d_ws, size_t ws_size,
                              hipStream_t stream) {
    const float* x  = (const float*)d_in[0];
    const int*   ei = (const int*)d_in[1];
    const float* W1 = (const float*)d_in[2];
    const float* b1 = (const float*)d_in[3];
    const float* W2 = (const float*)d_in[4];
    const float* b2 = (const float*)d_in[5];
    const int n  = in_sizes[0] / NCH;   // 100000
    const int ne = in_sizes[1] / 2;     // 1600000
    const int* src = ei;
    const int* dst = ei + ne;

    // workspace layout (all 256B-aligned)
    char* ws = (char*)d_ws;
    size_t off = 0;
    auto alloc = [&](size_t bytes) { void* p = ws + off; off += (bytes + 255) & ~(size_t)255; return p; };
    int*   cntCB   = (int*)alloc((size_t)CB * NBLK * 4);       // 1 MB
    int*   binTot  = (int*)alloc((size_t)CB * 4);
    int*   cb      = (int*)alloc((size_t)(CB + 1) * 4);
    int*   rowptr  = (int*)alloc((size_t)(n + 1) * 4);
    float* dinv    = (float*)alloc((size_t)n * 4);
    int*   csr     = (int*)alloc((size_t)ne * 4 + 128);        // +128B pad for tail loads
    int2*  coarse  = (int2*)alloc((size_t)ne * 8);             // 12.8 MB
    uint*  hsB     = (uint*)alloc((size_t)n * 32 * 4);         // 12.8 MB (gemm out, bf16)
    uint*  hsB2    = (uint*)alloc((size_t)n * 32 * 4);         // 12.8 MB (agg1 out, relu bf16)
    uint4* wfrag   = (uint4*)alloc(1024 * 16);                 // 16 KB (both layers' B-frags)

    const int blk = 256;
    const int gAgg = (n * 64 + blk - 1) / blk;                 // wave per node
    const int epb  = (ne + NBLK - 1) / NBLK;
    const int nBuck = (n + 255) / 256;
    const int nWaveG = (n + 15) / 16;                          // 16 rows per wave
    const int gGemm = (nWaveG + 3) / 4;                        // 4 waves per block

    // ---- CSR build (no global atomics) + W fragment pack ----
    wfrag_kernel         <<<4, 256, 0, stream>>>(W1, W2, wfrag);
    coarse_hist_kernel   <<<NBLK, blk, 0, stream>>>(dst, cntCB, ne, epb);
    binscan_kernel       <<<CB, NBLK, 0, stream>>>(cntCB, binTot);
    cbscan_kernel        <<<1, CB, 0, stream>>>(binTot, cb, rowptr, n, ne);
    coarse_scatter_kernel<<<NBLK, blk, 0, stream>>>(src, dst, cntCB, cb, coarse, ne, epb);
    bucket_kernel        <<<nBuck, 256, 0, stream>>>(coarse, cb, rowptr, dinv, csr, n);

    // ---- layer 1 ----
    gemm_mfma_kernel<false><<<gGemm, blk, 0, stream>>>(x, wfrag, dinv, hsB, n);
    agg_kernel<true><<<gAgg, blk, 0, stream>>>(hsB, rowptr, csr, dinv, b1, hsB2, n);

    // ---- layer 2 (relu pre-applied by agg1; A read as packed bf16) ----
    gemm_mfma_kernel<true><<<gGemm, blk, 0, stream>>>(hsB2, wfrag + 512, dinv, hsB, n);
    agg_kernel<false><<<gAgg, blk, 0, stream>>>(hsB, rowptr, csr, dinv, b2, d_out, n);
}